// Round 4
// baseline (44.098 us; speedup 1.0000x reference)
//
#include <hip/hip_runtime.h>
#include <cmath>

// Bokeh render, gather form:
// out[b,c,y,x] = sum_{dy,dx in [-4,4]} w * img[b,c,y-dy,x-dx] / sum w
// w = sigmoid(8*(r_src - dist)) / max(pi*r_src^2,1),
//     masked by max(|dy|,|dx|) <= floor(r_src)+1 and src in-bounds.
//
// R3 DIAGNOSTIC ROUND: R1/R2 structural changes (spill fix, 2x occupancy)
// left dur pinned at ~27us; pipe models say ~17us. The kernel never shows in
// rocprof top-5 (harness 256MB fills at 38-40us fill all slots). This round
// runs the main loop TWICE (pass 0 -> d_out, pass 1 -> d_ws, identical
// deterministic values) to (a) lift the kernel into top-5 for counters and
// (b) decompose dur: dur(2pass) - 27us = pure main-loop marginal cost.

#define HH 512
#define WW 512
#define NB 2
#define TILE 32
#define HALO 4
#define SROWS (TILE + 2 * HALO)   // 40
#define LW 44                     // LDS row stride (16B-aligned, conflict-free)

__global__ __launch_bounds__(256, 2) void bokeh_gather(
    const float* __restrict__ img,
    const float* __restrict__ def,
    float* __restrict__ out,
    float* __restrict__ out2)
{
  __shared__ __align__(16) float sG[SROWS][LW];
  __shared__ __align__(16) float sIv[SROWS][LW];
  __shared__ __align__(16) float sI0[SROWS][LW];
  __shared__ __align__(16) float sI1[SROWS][LW];
  __shared__ __align__(16) float sI2[SROWS][LW];
  __shared__ float sFd[9][12];  // exp(8*dist) per (dy,dx)
  __shared__ float sTh[9][12];  // exp(-8*(m-1)) per (dy,dx)

  const int tid = threadIdx.x;
  const int tx = tid & 7;        // 8 threads * 4 px = 32 cols
  const int ty = tid >> 3;       // 32 rows
  const int bx = blockIdx.x * TILE;
  const int by = blockIdx.y * TILE;
  const int b  = blockIdx.z;

  if (tid < 81) {
    int dyi = tid / 9, dxi = tid - dyi * 9;
    int dyo = dyi - 4, dxo = dxi - 4;
    int ady = dyo < 0 ? -dyo : dyo;
    int adx = dxo < 0 ? -dxo : dxo;
    int m = ady > adx ? ady : adx;
    float d2 = (float)(dyo * dyo + dxo * dxo);
    sFd[dyi][dxi] = __expf(8.0f * sqrtf(d2));
    sTh[dyi][dxi] = __expf(-8.0f * (float)(m - 1));
  }

  const float* dpt = def + b * (HH * WW);
  const float* ipt = img + b * (3 * HH * WW);

  // Stage halo'd source tile. OOB sources -> zeros => weight exactly 0.
  for (int idx = tid; idx < SROWS * SROWS; idx += 256) {
    int ly = idx / SROWS;
    int lx = idx - ly * SROWS;
    int sy = by - HALO + ly;
    int sx = bx - HALO + lx;
    float G = 0.f, iv = 0.f, a0 = 0.f, a1 = 0.f, a2 = 0.f;
    if (sy >= 0 && sy < HH && sx >= 0 && sx < WW) {
      int o = sy * WW + sx;
      float r = fabsf(dpt[o]);
      G  = __expf(-8.0f * r);
      iv = __builtin_amdgcn_rcpf(fmaxf(3.14159265358979f * r * r, 1.0f));
      a0 = ipt[o];
      a1 = ipt[o + HH * WW];
      a2 = ipt[o + 2 * HH * WW];
    }
    sG[ly][lx]  = G;
    sIv[ly][lx] = iv;
    sI0[ly][lx] = a0;
    sI1[ly][lx] = a1;
    sI2[ly][lx] = a2;
  }
  __syncthreads();

  const int col0 = 4 * tx;  // LDS col of source-window start (16B aligned)
  const int oy = by + ty;
  const int ox = bx + col0;

  #pragma unroll 1
  for (int pass = 0; pass < 2; ++pass) {
    // Force the second pass to re-read LDS / recompute (no CSE across passes).
    asm volatile("" ::: "memory");

    float wsum[4] = {0.f, 0.f, 0.f, 0.f};
    float ac0[4]  = {0.f, 0.f, 0.f, 0.f};
    float ac1[4]  = {0.f, 0.f, 0.f, 0.f};
    float ac2[4]  = {0.f, 0.f, 0.f, 0.f};

    #pragma unroll 1
    for (int dy = 0; dy < 9; ++dy) {
      const int sr = ty + dy;
      float fdr[9], thv[9];
      #pragma unroll
      for (int x = 0; x < 9; ++x) { fdr[x] = sFd[dy][x]; thv[x] = sTh[dy][x]; }

      const float* rG = &sG[sr][col0];
      const float* rI = &sIv[sr][col0];
      const float* r0 = &sI0[sr][col0];
      const float* r1 = &sI1[sr][col0];
      const float* r2 = &sI2[sr][col0];
      float Gv[12], Iv[12], P0[12], P1[12], P2[12];
      #pragma unroll
      for (int q = 0; q < 3; ++q) {
        *(float4*)&Gv[4 * q] = *(const float4*)(rG + 4 * q);
        *(float4*)&Iv[4 * q] = *(const float4*)(rI + 4 * q);
        *(float4*)&P0[4 * q] = *(const float4*)(r0 + 4 * q);
        *(float4*)&P1[4 * q] = *(const float4*)(r1 + 4 * q);
        *(float4*)&P2[4 * q] = *(const float4*)(r2 + 4 * q);
      }
      #pragma unroll
      for (int k = 0; k < 4; ++k) {
        #pragma unroll
        for (int j = k; j < k + 9; ++j) {
          const int xi = j - k;                    // = dxo + 4, compile-time
          const float Fd = fdr[xi];
          const float th = thv[xi];
          float g = Gv[j];
          float tden = fmaf(g, Fd, 1.0f);          // 1 + e^{-8r} e^{8d}
          float w = __builtin_amdgcn_rcpf(tden) * Iv[j];
          w = (g <= th) ? w : 0.0f;                // window mask (r >= m-1)
          wsum[k] += w;
          ac0[k] = fmaf(w, P0[j], ac0[k]);
          ac1[k] = fmaf(w, P1[j], ac1[k]);
          ac2[k] = fmaf(w, P2[j], ac2[k]);
        }
      }
    }

    float rw[4];
    #pragma unroll
    for (int k = 0; k < 4; ++k) rw[k] = __builtin_amdgcn_rcpf(wsum[k]);

    float* dst = pass ? out2 : out;
    float* op0 = dst + ((b * 3 + 0) * HH + oy) * WW + ox;
    float* op1 = dst + ((b * 3 + 1) * HH + oy) * WW + ox;
    float* op2 = dst + ((b * 3 + 2) * HH + oy) * WW + ox;
    float4 v0, v1, v2;
    v0.x = ac0[0] * rw[0]; v0.y = ac0[1] * rw[1]; v0.z = ac0[2] * rw[2]; v0.w = ac0[3] * rw[3];
    v1.x = ac1[0] * rw[0]; v1.y = ac1[1] * rw[1]; v1.z = ac1[2] * rw[2]; v1.w = ac1[3] * rw[3];
    v2.x = ac2[0] * rw[0]; v2.y = ac2[1] * rw[1]; v2.z = ac2[2] * rw[2]; v2.w = ac2[3] * rw[3];
    *(float4*)op0 = v0;
    *(float4*)op1 = v1;
    *(float4*)op2 = v2;
  }
}

extern "C" void kernel_launch(void* const* d_in, const int* in_sizes, int n_in,
                              void* d_out, int out_size, void* d_ws, size_t ws_size,
                              hipStream_t stream) {
  const float* img = (const float*)d_in[0];   // (2,3,512,512) f32
  const float* def = (const float*)d_in[1];   // (2,1,512,512) f32
  float* out = (float*)d_out;                 // (2,3,512,512) f32
  // Pass-1 sink: d_ws if large enough, else harmlessly rewrite d_out
  // (identical values either way -> deterministic).
  float* out2 = (ws_size >= (size_t)out_size * sizeof(float))
                    ? (float*)d_ws : out;

  dim3 grid(WW / TILE, HH / TILE, NB);
  dim3 block(256);
  hipLaunchKernelGGL(bokeh_gather, grid, block, 0, stream, img, def, out, out2);
}

// Round 5
// 42.204 us; speedup vs baseline: 1.0449x; 1.0449x over previous
//
#include <hip/hip_runtime.h>
#include <cmath>

// Bokeh render, gather form:
// out[b,c,y,x] = sum_{dy,dx in [-4,4]} w * img[b,c,y-dy,x-dx] / sum w
// w = sigmoid(8*(r_src - dist)) / max(pi*r_src^2,1),
//     masked by max(|dy|,|dx|) <= floor(r_src)+1 and src in-bounds.
//
// R4: bank-conflict fix. R3 counters: SQ_LDS_BANK_CONFLICT = 12.47M
// (~22.5 cyc per ds_read_b128, ~20us/dispatch of stalls). Cause: with
// tx=tid&7 each 16-lane LDS phase spanned 2+ tile rows (row stride 44
// dwords) -> same bank-quad hit with multiple different-row addresses.
// Fix: tx=tid&15, 64-wide tile, row stride 72 dwords -> each 16-lane
// phase reads ONE row; same-quad collisions are the proven stride-32-dword
// pattern (m134, ~12cyc). Still 2-pass (pass1 -> d_ws) so the kernel stays
// in rocprof top-5 for a clean counter A/B vs R3.

#define HH 512
#define WW 512
#define NB 2
#define TW 64                     // tile width
#define TH 32                     // tile height
#define HALO 4
#define SROWS (TH + 2 * HALO)     // 40
#define LW 72                     // row stride in dwords: [4][64][4]

__global__ __launch_bounds__(512, 2) void bokeh_gather(
    const float* __restrict__ img,
    const float* __restrict__ def,
    float* __restrict__ out,
    float* __restrict__ out2)
{
  __shared__ __align__(16) float sG[SROWS][LW];
  __shared__ __align__(16) float sIv[SROWS][LW];
  __shared__ __align__(16) float sI0[SROWS][LW];
  __shared__ __align__(16) float sI1[SROWS][LW];
  __shared__ __align__(16) float sI2[SROWS][LW];
  __shared__ float sFd[9][12];  // exp(8*dist) per (dy,dx)
  __shared__ float sTh[9][12];  // exp(-8*(m-1)) per (dy,dx)

  const int tid = threadIdx.x;
  const int tx = tid & 15;       // 16 threads * 4 px = 64 cols
  const int ty = tid >> 4;       // 32 rows
  const int bx = blockIdx.x * TW;
  const int by = blockIdx.y * TH;
  const int b  = blockIdx.z;

  if (tid < 81) {
    int dyi = tid / 9, dxi = tid - dyi * 9;
    int dyo = dyi - 4, dxo = dxi - 4;
    int ady = dyo < 0 ? -dyo : dyo;
    int adx = dxo < 0 ? -dxo : dxo;
    int m = ady > adx ? ady : adx;
    float d2 = (float)(dyo * dyo + dxo * dxo);
    sFd[dyi][dxi] = __expf(8.0f * sqrtf(d2));
    sTh[dyi][dxi] = __expf(-8.0f * (float)(m - 1));
  }

  const float* dpt = def + b * (HH * WW);
  const float* ipt = img + b * (3 * HH * WW);

  // Stage halo'd source tile. OOB sources -> zeros => weight exactly 0.
  for (int idx = tid; idx < SROWS * LW; idx += 512) {
    int ly = idx / LW;
    int lx = idx - ly * LW;
    int sy = by - HALO + ly;
    int sx = bx - HALO + lx;
    float G = 0.f, iv = 0.f, a0 = 0.f, a1 = 0.f, a2 = 0.f;
    if (sy >= 0 && sy < HH && sx >= 0 && sx < WW) {
      int o = sy * WW + sx;
      float r = fabsf(dpt[o]);
      G  = __expf(-8.0f * r);
      iv = __builtin_amdgcn_rcpf(fmaxf(3.14159265358979f * r * r, 1.0f));
      a0 = ipt[o];
      a1 = ipt[o + HH * WW];
      a2 = ipt[o + 2 * HH * WW];
    }
    sG[ly][lx]  = G;
    sIv[ly][lx] = iv;
    sI0[ly][lx] = a0;
    sI1[ly][lx] = a1;
    sI2[ly][lx] = a2;
  }
  __syncthreads();

  const int col0 = 4 * tx;  // LDS col of source-window start (16B aligned)
  const int oy = by + ty;
  const int ox = bx + col0;

  #pragma unroll 1
  for (int pass = 0; pass < 2; ++pass) {
    // Force the second pass to re-read LDS / recompute (no CSE across passes).
    asm volatile("" ::: "memory");

    float wsum[4] = {0.f, 0.f, 0.f, 0.f};
    float ac0[4]  = {0.f, 0.f, 0.f, 0.f};
    float ac1[4]  = {0.f, 0.f, 0.f, 0.f};
    float ac2[4]  = {0.f, 0.f, 0.f, 0.f};

    #pragma unroll 1
    for (int dy = 0; dy < 9; ++dy) {
      const int sr = ty + dy;
      float fdr[9], thv[9];
      #pragma unroll
      for (int x = 0; x < 9; ++x) { fdr[x] = sFd[dy][x]; thv[x] = sTh[dy][x]; }

      const float* rG = &sG[sr][col0];
      const float* rI = &sIv[sr][col0];
      const float* r0 = &sI0[sr][col0];
      const float* r1 = &sI1[sr][col0];
      const float* r2 = &sI2[sr][col0];
      float Gv[12], Iv[12], P0[12], P1[12], P2[12];
      #pragma unroll
      for (int q = 0; q < 3; ++q) {
        *(float4*)&Gv[4 * q] = *(const float4*)(rG + 4 * q);
        *(float4*)&Iv[4 * q] = *(const float4*)(rI + 4 * q);
        *(float4*)&P0[4 * q] = *(const float4*)(r0 + 4 * q);
        *(float4*)&P1[4 * q] = *(const float4*)(r1 + 4 * q);
        *(float4*)&P2[4 * q] = *(const float4*)(r2 + 4 * q);
      }
      #pragma unroll
      for (int k = 0; k < 4; ++k) {
        #pragma unroll
        for (int j = k; j < k + 9; ++j) {
          const int xi = j - k;                    // = dxo + 4, compile-time
          const float Fd = fdr[xi];
          const float th = thv[xi];
          float g = Gv[j];
          float tden = fmaf(g, Fd, 1.0f);          // 1 + e^{-8r} e^{8d}
          float w = __builtin_amdgcn_rcpf(tden) * Iv[j];
          w = (g <= th) ? w : 0.0f;                // window mask (r >= m-1)
          wsum[k] += w;
          ac0[k] = fmaf(w, P0[j], ac0[k]);
          ac1[k] = fmaf(w, P1[j], ac1[k]);
          ac2[k] = fmaf(w, P2[j], ac2[k]);
        }
      }
    }

    float rw[4];
    #pragma unroll
    for (int k = 0; k < 4; ++k) rw[k] = __builtin_amdgcn_rcpf(wsum[k]);

    float* dst = pass ? out2 : out;
    float* op0 = dst + ((b * 3 + 0) * HH + oy) * WW + ox;
    float* op1 = dst + ((b * 3 + 1) * HH + oy) * WW + ox;
    float* op2 = dst + ((b * 3 + 2) * HH + oy) * WW + ox;
    float4 v0, v1, v2;
    v0.x = ac0[0] * rw[0]; v0.y = ac0[1] * rw[1]; v0.z = ac0[2] * rw[2]; v0.w = ac0[3] * rw[3];
    v1.x = ac1[0] * rw[0]; v1.y = ac1[1] * rw[1]; v1.z = ac1[2] * rw[2]; v1.w = ac1[3] * rw[3];
    v2.x = ac2[0] * rw[0]; v2.y = ac2[1] * rw[1]; v2.z = ac2[2] * rw[2]; v2.w = ac2[3] * rw[3];
    *(float4*)op0 = v0;
    *(float4*)op1 = v1;
    *(float4*)op2 = v2;
  }
}

extern "C" void kernel_launch(void* const* d_in, const int* in_sizes, int n_in,
                              void* d_out, int out_size, void* d_ws, size_t ws_size,
                              hipStream_t stream) {
  const float* img = (const float*)d_in[0];   // (2,3,512,512) f32
  const float* def = (const float*)d_in[1];   // (2,1,512,512) f32
  float* out = (float*)d_out;                 // (2,3,512,512) f32
  float* out2 = (ws_size >= (size_t)out_size * sizeof(float))
                    ? (float*)d_ws : out;

  dim3 grid(WW / TW, HH / TH, NB);
  dim3 block(512);
  hipLaunchKernelGGL(bokeh_gather, grid, block, 0, stream, img, def, out, out2);
}

// Round 6
// 24.630 us; speedup vs baseline: 1.7904x; 1.7135x over previous
//
#include <hip/hip_runtime.h>
#include <cmath>

// Bokeh render, gather form:
// out[b,c,y,x] = sum_{dy,dx in [-4,4]} w * img[b,c,y-dy,x-dx] / sum w
// w = sigmoid(8*(r_src - dist)) / max(pi*r_src^2,1);  r = |defocus| in [0,4).
//
// R6: (a) WINDOW MASK DROPPED: for taps outside the ref's scatter window
// (max(|dy|,|dx|) > floor(r)+1) the weight sigmoid(8(r-d)) <= sigmoid(-8)
// ~3e-4 and the induced output shift is <~2e-5 (mass enters numerator AND
// denominator) -- far under the 1.86e-2 threshold. Saves 2 VALU/tap + the
// sTh table. OOB sources still exact via Iv=0.
// (b) 2-ROW REGISTER BLOCKING (8px/thread = 4w x 2r): each window row's
// 15 ds_read_b128 serves ~72 taps instead of 36 -> per-CU LDS instruction
// count halves. R4/R5 showed LDS-pipe (issue + ~20cyc/b128 conflicts) was
// the bottleneck (~14.6us/pass of 21us); VALU ~9us; HBM 6%.
// Conflict-rate models failed twice (R4, R5) -> attack count, not rate.

#define HH 512
#define WW 512
#define NB 2
#define TW 64                     // tile width
#define TH 32                     // tile height
#define HALO 4
#define SROWS (TH + 2 * HALO)     // 40
#define LW 72                     // row stride in dwords = 64 + 2*4 (exact)

__global__ __launch_bounds__(256) void bokeh_gather(
    const float* __restrict__ img,
    const float* __restrict__ def,
    float* __restrict__ out)
{
  __shared__ __align__(16) float sG[SROWS][LW];
  __shared__ __align__(16) float sIv[SROWS][LW];
  __shared__ __align__(16) float sI0[SROWS][LW];
  __shared__ __align__(16) float sI1[SROWS][LW];
  __shared__ __align__(16) float sI2[SROWS][LW];
  __shared__ float sFd[9][12];  // exp(8*dist) per (dy,dx)

  const int tid = threadIdx.x;
  const int tx  = tid & 15;      // 16 threads * 4 px = 64 cols
  const int tyq = tid >> 4;      // 16 thread-rows * 2 px = 32 rows
  const int bx = blockIdx.x * TW;
  const int by = blockIdx.y * TH;
  const int b  = blockIdx.z;

  if (tid < 81) {
    int dyi = tid / 9, dxi = tid - dyi * 9;
    int dyo = dyi - 4, dxo = dxi - 4;
    float d2 = (float)(dyo * dyo + dxo * dxo);
    sFd[dyi][dxi] = __expf(8.0f * sqrtf(d2));
  }

  const float* dpt = def + b * (HH * WW);
  const float* ipt = img + b * (3 * HH * WW);

  // Stage halo'd source tile. OOB sources -> zeros => weight exactly 0 (Iv=0).
  for (int idx = tid; idx < SROWS * LW; idx += 256) {
    int ly = idx / LW;
    int lx = idx - ly * LW;
    int sy = by - HALO + ly;
    int sx = bx - HALO + lx;
    float G = 0.f, iv = 0.f, a0 = 0.f, a1 = 0.f, a2 = 0.f;
    if (sy >= 0 && sy < HH && sx >= 0 && sx < WW) {
      int o = sy * WW + sx;
      float r = fabsf(dpt[o]);
      G  = __expf(-8.0f * r);
      iv = __builtin_amdgcn_rcpf(fmaxf(3.14159265358979f * r * r, 1.0f));
      a0 = ipt[o];
      a1 = ipt[o + HH * WW];
      a2 = ipt[o + 2 * HH * WW];
    }
    sG[ly][lx]  = G;
    sIv[ly][lx] = iv;
    sI0[ly][lx] = a0;
    sI1[ly][lx] = a1;
    sI2[ly][lx] = a2;
  }
  __syncthreads();

  // Accumulators for 2 output rows x 4 px.
  float wsum[2][4] = {{0.f,0.f,0.f,0.f},{0.f,0.f,0.f,0.f}};
  float ac0[2][4]  = {{0.f,0.f,0.f,0.f},{0.f,0.f,0.f,0.f}};
  float ac1[2][4]  = {{0.f,0.f,0.f,0.f},{0.f,0.f,0.f,0.f}};
  float ac2[2][4]  = {{0.f,0.f,0.f,0.f},{0.f,0.f,0.f,0.f}};

  const int col0 = 4 * tx;       // lds col of window start (16B aligned)
  const int row0 = 2 * tyq;      // lds row of first window row

  #pragma unroll 1
  for (int wr = 0; wr < 10; ++wr) {
    const int sr = row0 + wr;
    const float* rG = &sG[sr][col0];
    const float* rI = &sIv[sr][col0];
    const float* r0 = &sI0[sr][col0];
    const float* r1 = &sI1[sr][col0];
    const float* r2 = &sI2[sr][col0];
    float Gv[12], Iv[12], P0[12], P1[12], P2[12];
    #pragma unroll
    for (int q = 0; q < 3; ++q) {
      *(float4*)&Gv[4 * q] = *(const float4*)(rG + 4 * q);
      *(float4*)&Iv[4 * q] = *(const float4*)(rI + 4 * q);
      *(float4*)&P0[4 * q] = *(const float4*)(r0 + 4 * q);
      *(float4*)&P1[4 * q] = *(const float4*)(r1 + 4 * q);
      *(float4*)&P2[4 * q] = *(const float4*)(r2 + 4 * q);
    }
    // This window row serves output row o when dy = wr-4-o is in [-4,4].
    #pragma unroll
    for (int o = 0; o < 2; ++o) {
      const int dy4 = wr - o;              // = dy+4
      if (dy4 < 0 || dy4 > 8) continue;    // uniform branch (rows 0 and 9)
      float fdr[9];
      #pragma unroll
      for (int x = 0; x < 9; ++x) fdr[x] = sFd[dy4][x];
      #pragma unroll
      for (int k = 0; k < 4; ++k) {
        #pragma unroll
        for (int j = k; j < k + 9; ++j) {
          const int xi = j - k;            // = dxo + 4, compile-time
          float g = Gv[j];
          float tden = fmaf(g, fdr[xi], 1.0f);   // 1 + e^{-8r} e^{8d}
          float w = __builtin_amdgcn_rcpf(tden) * Iv[j];
          wsum[o][k] += w;
          ac0[o][k] = fmaf(w, P0[j], ac0[o][k]);
          ac1[o][k] = fmaf(w, P1[j], ac1[o][k]);
          ac2[o][k] = fmaf(w, P2[j], ac2[o][k]);
        }
      }
    }
  }

  const int ox = bx + col0;
  #pragma unroll
  for (int o = 0; o < 2; ++o) {
    const int oy = by + row0 + o;
    float rw[4];
    #pragma unroll
    for (int k = 0; k < 4; ++k) rw[k] = __builtin_amdgcn_rcpf(wsum[o][k]);
    float* op0 = out + ((b * 3 + 0) * HH + oy) * WW + ox;
    float* op1 = out + ((b * 3 + 1) * HH + oy) * WW + ox;
    float* op2 = out + ((b * 3 + 2) * HH + oy) * WW + ox;
    float4 v0, v1, v2;
    v0.x = ac0[o][0] * rw[0]; v0.y = ac0[o][1] * rw[1];
    v0.z = ac0[o][2] * rw[2]; v0.w = ac0[o][3] * rw[3];
    v1.x = ac1[o][0] * rw[0]; v1.y = ac1[o][1] * rw[1];
    v1.z = ac1[o][2] * rw[2]; v1.w = ac1[o][3] * rw[3];
    v2.x = ac2[o][0] * rw[0]; v2.y = ac2[o][1] * rw[1];
    v2.z = ac2[o][2] * rw[2]; v2.w = ac2[o][3] * rw[3];
    *(float4*)op0 = v0;
    *(float4*)op1 = v1;
    *(float4*)op2 = v2;
  }
}

extern "C" void kernel_launch(void* const* d_in, const int* in_sizes, int n_in,
                              void* d_out, int out_size, void* d_ws, size_t ws_size,
                              hipStream_t stream) {
  const float* img = (const float*)d_in[0];   // (2,3,512,512) f32
  const float* def = (const float*)d_in[1];   // (2,1,512,512) f32
  float* out = (float*)d_out;                 // (2,3,512,512) f32

  dim3 grid(WW / TW, HH / TH, NB);
  dim3 block(256);
  hipLaunchKernelGGL(bokeh_gather, grid, block, 0, stream, img, def, out);
}

// Round 7
// 20.595 us; speedup vs baseline: 2.1412x; 1.1959x over previous
//
#include <hip/hip_runtime.h>
#include <cmath>

// Bokeh render, gather form:
// out[b,c,y,x] = sum_{dy,dx in [-4,4]} w * img[b,c,y-dy,x-dx] / sum w
// w = sigmoid(8*(r_src - dist)) / max(pi*r_src^2,1);  r = |defocus| in [0,4).
// Window mask dropped (outside-window weight <= sigma(-8) -> output shift
// <2e-5, far under threshold). OOB sources exact via Iv=0.
//
// R7: per-CU LDS-pipe is the bottleneck (R4/R5 counters: VALU ~9us/pass,
// LDS+stall ~10us/pass; one LDS pipe per CU shared by 4 SIMDs). Lever:
// cut LDS instructions/px, keep 2 waves/SIMD.
//  - bf16-pack 20B/px -> 12B/px: sX=(G|Iv) bf16 pair, sY=(c0|c1) bf16 pair,
//    sZ=c2 as truncated f32 (no unpack needed). 15 -> 9 ds_read_b128/row.
//  - 4 px/thread, 512-thread blocks, tile 64x32: grid = 256 blocks = 1/CU,
//    2048 waves = 2 waves/SIMD, zero tail.
//  - unpack = and/lshl (bf16 hi/lo), 4 inst per loaded px per row.
// RTNE rounding at staging: absmax budget ~7e-3 vs 1.86e-2 threshold.

#define HH 512
#define WW 512
#define NB 2
#define TW 64                     // tile width
#define TH 32                     // tile height
#define HALO 4
#define SROWS (TH + 2 * HALO)     // 40
#define LW 72                     // row stride in dwords = 64 + 2*4

__device__ __forceinline__ unsigned rtne_hi(float v) {
  // bf16 round-to-nearest-even, result in HIGH 16 bits (low 16 zero).
  unsigned u = __float_as_uint(v);
  u = u + 0x7FFFu + ((u >> 16) & 1u);
  return u & 0xFFFF0000u;
}

__global__ __launch_bounds__(512, 2) void bokeh_gather(
    const float* __restrict__ img,
    const float* __restrict__ def,
    float* __restrict__ out)
{
  __shared__ __align__(16) unsigned sX[SROWS][LW];  // G(hi) | Iv(lo)
  __shared__ __align__(16) unsigned sY[SROWS][LW];  // c0(hi) | c1(lo)
  __shared__ __align__(16) unsigned sZ[SROWS][LW];  // c2 as truncated f32
  __shared__ float sFd[9][12];                      // exp(8*dist) per (dy,dx)

  const int tid = threadIdx.x;
  const int tx  = tid & 15;      // 16 threads * 4 px = 64 cols
  const int ty  = tid >> 4;      // 32 rows
  const int bx = blockIdx.x * TW;
  const int by = blockIdx.y * TH;
  const int b  = blockIdx.z;

  if (tid < 81) {
    int dyi = tid / 9, dxi = tid - dyi * 9;
    int dyo = dyi - 4, dxo = dxi - 4;
    float d2 = (float)(dyo * dyo + dxo * dxo);
    sFd[dyi][dxi] = __expf(8.0f * sqrtf(d2));
  }

  const float* dpt = def + b * (HH * WW);
  const float* ipt = img + b * (3 * HH * WW);

  // Stage halo'd source tile, bf16-packed. OOB -> zeros => w = 0 exactly.
  for (int idx = tid; idx < SROWS * LW; idx += 512) {
    int ly = idx / LW;
    int lx = idx - ly * LW;
    int sy = by - HALO + ly;
    int sx = bx - HALO + lx;
    unsigned X = 0u, Y = 0u, Z = 0u;
    if (sy >= 0 && sy < HH && sx >= 0 && sx < WW) {
      int o = sy * WW + sx;
      float r = fabsf(dpt[o]);
      float G  = __expf(-8.0f * r);
      float iv = __builtin_amdgcn_rcpf(fmaxf(3.14159265358979f * r * r, 1.0f));
      X = rtne_hi(G) | (rtne_hi(iv) >> 16);
      Y = rtne_hi(ipt[o]) | (rtne_hi(ipt[o + HH * WW]) >> 16);
      Z = rtne_hi(ipt[o + 2 * HH * WW]);
    }
    sX[ly][lx] = X;
    sY[ly][lx] = Y;
    sZ[ly][lx] = Z;
  }
  __syncthreads();

  float wsum[4] = {0.f, 0.f, 0.f, 0.f};
  float ac0[4]  = {0.f, 0.f, 0.f, 0.f};
  float ac1[4]  = {0.f, 0.f, 0.f, 0.f};
  float ac2[4]  = {0.f, 0.f, 0.f, 0.f};

  const int col0 = 4 * tx;       // lds col of window start (16B aligned)

  #pragma unroll 1
  for (int dy = 0; dy < 9; ++dy) {
    const int sr = ty + dy;
    float fdr[9];
    #pragma unroll
    for (int x = 0; x < 9; ++x) fdr[x] = sFd[dy][x];

    unsigned Xv[12], Yv[12], Zv[12];
    #pragma unroll
    for (int q = 0; q < 3; ++q) {
      *(uint4*)&Xv[4 * q] = *(const uint4*)(&sX[sr][col0] + 4 * q);
      *(uint4*)&Yv[4 * q] = *(const uint4*)(&sY[sr][col0] + 4 * q);
      *(uint4*)&Zv[4 * q] = *(const uint4*)(&sZ[sr][col0] + 4 * q);
    }
    // Unpack bf16 pairs -> f32 (hi: mask, lo: shift). Zv is already f32.
    float Gv[12], Iv[12], C0[12], C1[12];
    #pragma unroll
    for (int j = 0; j < 12; ++j) {
      Gv[j] = __uint_as_float(Xv[j] & 0xFFFF0000u);
      Iv[j] = __uint_as_float(Xv[j] << 16);
      C0[j] = __uint_as_float(Yv[j] & 0xFFFF0000u);
      C1[j] = __uint_as_float(Yv[j] << 16);
    }

    #pragma unroll
    for (int k = 0; k < 4; ++k) {
      #pragma unroll
      for (int j = k; j < k + 9; ++j) {
        const int xi = j - k;                  // = dxo + 4, compile-time
        float tden = fmaf(Gv[j], fdr[xi], 1.0f);   // 1 + e^{-8r} e^{8d}
        float w = __builtin_amdgcn_rcpf(tden) * Iv[j];
        wsum[k] += w;
        ac0[k] = fmaf(w, C0[j], ac0[k]);
        ac1[k] = fmaf(w, C1[j], ac1[k]);
        ac2[k] = fmaf(w, __uint_as_float(Zv[j]), ac2[k]);
      }
    }
  }

  const int oy = by + ty;
  const int ox = bx + col0;
  float rw[4];
  #pragma unroll
  for (int k = 0; k < 4; ++k) rw[k] = __builtin_amdgcn_rcpf(wsum[k]);

  float* op0 = out + ((b * 3 + 0) * HH + oy) * WW + ox;
  float* op1 = out + ((b * 3 + 1) * HH + oy) * WW + ox;
  float* op2 = out + ((b * 3 + 2) * HH + oy) * WW + ox;
  float4 v0, v1, v2;
  v0.x = ac0[0] * rw[0]; v0.y = ac0[1] * rw[1]; v0.z = ac0[2] * rw[2]; v0.w = ac0[3] * rw[3];
  v1.x = ac1[0] * rw[0]; v1.y = ac1[1] * rw[1]; v1.z = ac1[2] * rw[2]; v1.w = ac1[3] * rw[3];
  v2.x = ac2[0] * rw[0]; v2.y = ac2[1] * rw[1]; v2.z = ac2[2] * rw[2]; v2.w = ac2[3] * rw[3];
  *(float4*)op0 = v0;
  *(float4*)op1 = v1;
  *(float4*)op2 = v2;
}

extern "C" void kernel_launch(void* const* d_in, const int* in_sizes, int n_in,
                              void* d_out, int out_size, void* d_ws, size_t ws_size,
                              hipStream_t stream) {
  const float* img = (const float*)d_in[0];   // (2,3,512,512) f32
  const float* def = (const float*)d_in[1];   // (2,1,512,512) f32
  float* out = (float*)d_out;                 // (2,3,512,512) f32

  dim3 grid(WW / TW, HH / TH, NB);            // 8 x 16 x 2 = 256 blocks = 1/CU
  dim3 block(512);
  hipLaunchKernelGGL(bokeh_gather, grid, block, 0, stream, img, def, out);
}